// Round 5
// baseline (596.750 us; speedup 1.0000x reference)
//
#include <hip/hip_runtime.h>
#include <hip/hip_bf16.h>

#define NN 16384
#define TT 4
#define HH 64
#define NT (NN * TT)
#define CAP 128  // bucket capacity per node per edge-set; Poisson(16) => P(deg>=128) ~ 0
#define NEG_SLOPE 0.2f
#define LN_EPS 1e-5f
#define MEGA_BLOCKS 512  // 2 blocks/CU on 256 CUs -> all co-resident (required by gridbar)

typedef __attribute__((ext_vector_type(8))) short short8;   // 8 bf16 (4 VGPRs)
typedef __attribute__((ext_vector_type(4))) float f32x4;    // MFMA accumulator

__device__ __forceinline__ float bf2f(unsigned short u) {
    return __uint_as_float((unsigned)u << 16);
}
// f32 -> bf16 RNE, layout-independent
__device__ __forceinline__ unsigned short f2bf(float f) {
    unsigned u = __float_as_uint(f);
    return (unsigned short)((u + 0x7FFF + ((u >> 16) & 1)) >> 16);
}

// ---------------- device-wide barrier ----------------
// Sense-reversing barrier on bar[0]=count, bar[1]=generation. SAFE ONLY because
// all MEGA_BLOCKS blocks are guaranteed co-resident: 256 thr (4 waves), LDS=0,
// __launch_bounds__(256,2) caps VGPR at 256 -> >=2 blocks/CU * 256 CU = 512.
// __threadfence() is an agent-scope fence (L2 writeback + invalidate) -> data
// written before the barrier is visible across XCDs after it.

__device__ __forceinline__ void gridbar(int* bar) {
    __syncthreads();
    if (threadIdx.x == 0) {
        __threadfence();
        int g = __hip_atomic_load(&bar[1], __ATOMIC_RELAXED, __HIP_MEMORY_SCOPE_AGENT);
        int a = atomicAdd(&bar[0], 1);  // device-scope
        if (a == MEGA_BLOCKS - 1) {
            __hip_atomic_store(&bar[0], 0, __ATOMIC_RELAXED, __HIP_MEMORY_SCOPE_AGENT);
            __hip_atomic_store(&bar[1], g + 1, __ATOMIC_RELEASE, __HIP_MEMORY_SCOPE_AGENT);
        } else {
            while (__hip_atomic_load(&bar[1], __ATOMIC_ACQUIRE, __HIP_MEMORY_SCOPE_AGENT) == g)
                __builtin_amdgcn_s_sleep(2);
        }
        __threadfence();
    }
    __syncthreads();
}

// ---------------- prep: zero counters + barrier, pack W fragments ----------------
// blocks 0..127: zero cnt2 (2*NN ints); block 0 also zeros bar[0..1].
// blocks 128..135: pack the four 64x64 f32 W matrices into bf16 MFMA B-fragment
// layout: wpack[mat*512 + (c*2+ks)*64 + lane] = short8 of W[k=ks*32+quad*8+j][n=c*16+m].

__global__ __launch_bounds__(256) void prep_kernel(
    const float* __restrict__ W0s_, const float* __restrict__ W0f_,
    const float* __restrict__ W1s_, const float* __restrict__ W1f_,
    short8* __restrict__ wpack, int* __restrict__ cnt2, int* __restrict__ bar) {
    const int b = blockIdx.x;
    if (b < 128) {
        cnt2[b * 256 + threadIdx.x] = 0;
        if (b == 0 && threadIdx.x < 2) bar[threadIdx.x] = 0;
        return;
    }
    int id = (b - 128) * 256 + threadIdx.x;   // [0, 2048)
    int mat = id >> 9;
    int slot = id & 511;
    int lane = slot & 63;
    int cks = slot >> 6;
    int c = cks >> 1, ks = cks & 1;
    int m = lane & 15, quad = lane >> 4;
    const float* W = (mat == 0) ? W0s_ : (mat == 1) ? W0f_ : (mat == 2) ? W1s_ : W1f_;
    short8 v;
#pragma unroll
    for (int j = 0; j < 8; j++) {
        int k = ks * 32 + quad * 8 + j;
        int n = c * 16 + m;
        v[j] = (short)f2bf(W[k * 64 + n]);
    }
    wpack[id] = v;
}

// ---------------- phase bodies (inlined into mega kernel) ----------------

// atomic-ticket bucket scatter; after this, cnt2[] holds degrees.
__device__ __forceinline__ void scatter_body(const int* __restrict__ ei_s,
                                             const int* __restrict__ ei_f,
                                             int* __restrict__ cnt2,
                                             int* __restrict__ col2, int E) {
    for (int e0 = blockIdx.x * 256 + threadIdx.x; e0 < 2 * E; e0 += MEGA_BLOCKS * 256) {
        int e = e0;
        if (e < E) {
            int d = ei_s[E + e];
            int pos = atomicAdd(&cnt2[d], 1);
            if (pos < CAP) col2[d * CAP + pos] = ei_s[e];
        } else {
            e -= E;
            int d = ei_f[E + e];
            int pos = atomicAdd(&cnt2[NN + d], 1);
            if (pos < CAP) col2[(long)NN * CAP + d * CAP + pos] = ei_f[e];
        }
    }
}

// fused dual transform via MFMA: h_s = x*Ws, h_f = x*Wf + exp-scores.
// v_mfma_f32_16x16x32_bf16. A-frag: A[m=lane&15][k=quad*8+j]. B-frag (KxN):
// B[k=quad*8+j][n=lane&15]. C/D: col=lane&15, row=quad*4+reg.
// Wave = 32 rows; block = 4 waves = 128 rows; 512 blocks = NT rows exactly.
// Stores esc = exp(leakyrelu(score)) so the aggregate never runs exp.

__device__ __forceinline__ void transform_body(
    const float4* __restrict__ x4,
    const short8* __restrict__ wp_s, const float* __restrict__ as_,
    const short8* __restrict__ wp_f, const float* __restrict__ af,
    unsigned short* __restrict__ h_s, float* __restrict__ esc_s,
    unsigned short* __restrict__ h_f, float* __restrict__ esc_f) {
    const int lane = threadIdx.x & 63;
    const int wv = threadIdx.x >> 6;
    const int m = lane & 15;
    const int quad = lane >> 4;

    short8 Bs[4][2], Bf[4][2];
#pragma unroll
    for (int c = 0; c < 4; c++) {
#pragma unroll
        for (int ks = 0; ks < 2; ks++) {
            Bs[c][ks] = wp_s[(c * 2 + ks) * 64 + lane];
            Bf[c][ks] = wp_f[(c * 2 + ks) * 64 + lane];
        }
    }
    float a_s[4], a_f[4];
#pragma unroll
    for (int c = 0; c < 4; c++) { a_s[c] = as_[c * 16 + m]; a_f[c] = af[c * 16 + m]; }

    const int rowbase = blockIdx.x * 128 + wv * 32;
#pragma unroll
    for (int rt = 0; rt < 2; rt++) {
        const int row0 = rowbase + rt * 16;
        const long xbase = (long)(row0 + m) * 16 + quad * 2;
        float4 xa = x4[xbase];
        float4 xb = x4[xbase + 1];
        float4 xc = x4[xbase + 8];
        float4 xd = x4[xbase + 9];
        short8 A0, A1;
        A0[0] = (short)f2bf(xa.x); A0[1] = (short)f2bf(xa.y);
        A0[2] = (short)f2bf(xa.z); A0[3] = (short)f2bf(xa.w);
        A0[4] = (short)f2bf(xb.x); A0[5] = (short)f2bf(xb.y);
        A0[6] = (short)f2bf(xb.z); A0[7] = (short)f2bf(xb.w);
        A1[0] = (short)f2bf(xc.x); A1[1] = (short)f2bf(xc.y);
        A1[2] = (short)f2bf(xc.z); A1[3] = (short)f2bf(xc.w);
        A1[4] = (short)f2bf(xd.x); A1[5] = (short)f2bf(xd.y);
        A1[6] = (short)f2bf(xd.z); A1[7] = (short)f2bf(xd.w);

        f32x4 accs[4], accf[4];
#pragma unroll
        for (int c = 0; c < 4; c++) {
            accs[c] = (f32x4){0.f, 0.f, 0.f, 0.f};
            accf[c] = (f32x4){0.f, 0.f, 0.f, 0.f};
        }
#pragma unroll
        for (int c = 0; c < 4; c++) {
            accs[c] = __builtin_amdgcn_mfma_f32_16x16x32_bf16(A0, Bs[c][0], accs[c], 0, 0, 0);
            accs[c] = __builtin_amdgcn_mfma_f32_16x16x32_bf16(A1, Bs[c][1], accs[c], 0, 0, 0);
            accf[c] = __builtin_amdgcn_mfma_f32_16x16x32_bf16(A0, Bf[c][0], accf[c], 0, 0, 0);
            accf[c] = __builtin_amdgcn_mfma_f32_16x16x32_bf16(A1, Bf[c][1], accf[c], 0, 0, 0);
        }
#pragma unroll
        for (int reg = 0; reg < 4; reg++) {
            const int row = row0 + quad * 4 + reg;
            float ps = 0.f, pf = 0.f;
#pragma unroll
            for (int c = 0; c < 4; c++) {
                h_s[(long)row * 64 + c * 16 + m] = f2bf(accs[c][reg]);
                h_f[(long)row * 64 + c * 16 + m] = f2bf(accf[c][reg]);
                ps = fmaf(accs[c][reg], a_s[c], ps);
                pf = fmaf(accf[c][reg], a_f[c], pf);
            }
#pragma unroll
            for (int off = 1; off < 16; off <<= 1) {
                ps += __shfl_xor(ps, off, 64);
                pf += __shfl_xor(pf, off, 64);
            }
            if (m == 0) {
                float ls = (ps > 0.f) ? ps : NEG_SLOPE * ps;  // LeakyReLU folded in
                float lf = (pf > 0.f) ? pf : NEG_SLOPE * pf;
                esc_s[row] = __expf(ls);  // pre-exponentiated score
                esc_f[row] = __expf(lf);
            }
        }
    }
}

// attention aggregation (r3-proven inner loop). Wave handles 8 nodes
// sequentially; per node the full edge list is preloaded with one coalesced
// 64-wide load per set, indices broadcast via v_readlane (SGPR address math),
// gathers issued in independent batches of 8 per set, both sets interleaved.
// lane: t = lane>>4, channels 4*(lane&15)..+3.

__device__ __forceinline__ void aggregate_body(
    const float4* __restrict__ x4,
    const ushort4* __restrict__ hs4, const float* __restrict__ escs,
    const int* __restrict__ cnts, const int* __restrict__ cols,
    const ushort4* __restrict__ hf4, const float* __restrict__ escf,
    const int* __restrict__ cntf, const int* __restrict__ colf,
    const float4* __restrict__ g4, const float4* __restrict__ b4,
    float4* __restrict__ out4) {
    const int wv = threadIdx.x >> 6;
    const int lane = threadIdx.x & 63;
    const int t = lane >> 4;
    const int ci = lane & 15;
    const float4 gv = g4[ci], bv = b4[ci];
    const int n0 = (blockIdx.x * 4 + wv) * 8;

    for (int i = 0; i < 8; ++i) {
        const int n = n0 + i;
        int cS = cnts[n]; if (cS > CAP) cS = CAP;
        int cF = cntf[n]; if (cF > CAP) cF = CAP;
        cS = __builtin_amdgcn_readfirstlane(cS);
        cF = __builtin_amdgcn_readfirstlane(cF);
        const int* colS = cols + (long)n * CAP;
        const int* colF = colf + (long)n * CAP;

        int idxS = colS[lane];
        int idxF = colF[lane];
        if (lane >= cS) idxS = 0;
        if (lane >= cF) idxF = 0;

        const int cS64 = cS < 64 ? cS : 64;
        const int cF64 = cF < 64 ? cF : 64;

        float dS = 0.f, sx = 0.f, sy = 0.f, sz = 0.f, sw = 0.f;
        float dF = 0.f, fx = 0.f, fy = 0.f, fz = 0.f, fw = 0.f;

        const int nbS = (cS64 + 7) >> 3;
        const int nbF = (cF64 + 7) >> 3;
        const int nb = nbS > nbF ? nbS : nbF;

        for (int it = 0; it < nb; ++it) {
            const int j = it << 3;
            const bool doS = it < nbS;
            const bool doF = it < nbF;
            int sS[8], sF[8];
            float eS[8], eF[8];
            ushort4 hS[8], hF[8];

            if (doS) {
#pragma unroll
                for (int u = 0; u < 8; u++) sS[u] = __builtin_amdgcn_readlane(idxS, j + u);
#pragma unroll
                for (int u = 0; u < 8; u++) hS[u] = hs4[sS[u] * 64 + lane];
#pragma unroll
                for (int u = 0; u < 8; u++) eS[u] = escs[sS[u] * 4 + t];
            }
            if (doF) {
#pragma unroll
                for (int u = 0; u < 8; u++) sF[u] = __builtin_amdgcn_readlane(idxF, j + u);
#pragma unroll
                for (int u = 0; u < 8; u++) hF[u] = hf4[sF[u] * 64 + lane];
#pragma unroll
                for (int u = 0; u < 8; u++) eF[u] = escf[sF[u] * 4 + t];
            }
            if (doS) {
#pragma unroll
                for (int u = 0; u < 8; u++) {
                    float e = (j + u < cS64) ? eS[u] : 0.f;
                    dS += e;
                    sx = fmaf(e, bf2f(hS[u].x), sx);
                    sy = fmaf(e, bf2f(hS[u].y), sy);
                    sz = fmaf(e, bf2f(hS[u].z), sz);
                    sw = fmaf(e, bf2f(hS[u].w), sw);
                }
            }
            if (doF) {
#pragma unroll
                for (int u = 0; u < 8; u++) {
                    float e = (j + u < cF64) ? eF[u] : 0.f;
                    dF += e;
                    fx = fmaf(e, bf2f(hF[u].x), fx);
                    fy = fmaf(e, bf2f(hF[u].y), fy);
                    fz = fmaf(e, bf2f(hF[u].z), fz);
                    fw = fmaf(e, bf2f(hF[u].w), fw);
                }
            }
        }

        // tail beyond 64 edges (statistically unreachable; correctness guard)
        for (int j2 = 64; j2 < cS; ++j2) {
            int s0 = colS[j2];
            float e0 = escs[s0 * 4 + t];
            ushort4 h0 = hs4[(long)s0 * 64 + lane];
            dS += e0;
            sx = fmaf(e0, bf2f(h0.x), sx);
            sy = fmaf(e0, bf2f(h0.y), sy);
            sz = fmaf(e0, bf2f(h0.z), sz);
            sw = fmaf(e0, bf2f(h0.w), sw);
        }
        for (int j2 = 64; j2 < cF; ++j2) {
            int s0 = colF[j2];
            float e0 = escf[s0 * 4 + t];
            ushort4 h0 = hf4[(long)s0 * 64 + lane];
            dF += e0;
            fx = fmaf(e0, bf2f(h0.x), fx);
            fy = fmaf(e0, bf2f(h0.y), fy);
            fz = fmaf(e0, bf2f(h0.z), fz);
            fw = fmaf(e0, bf2f(h0.w), fw);
        }

        float msx = 0.f, msy = 0.f, msz = 0.f, msw = 0.f;
        if (dS > 0.f) {
            float r = 1.f / dS;
            msx = sx * r; msy = sy * r; msz = sz * r; msw = sw * r;
        }
        float mfx = 0.f, mfy = 0.f, mfz = 0.f, mfw = 0.f;
        if (dF > 0.f) {
            float r = 1.f / dF;
            mfx = fx * r; mfy = fy * r; mfz = fz * r; mfw = fw * r;
        }

        float4 xv = x4[(long)n * 64 + lane];  // x[n][t][4*ci..+3]
        float v0 = xv.x + 0.5f * (msx + mfx);
        float v1 = xv.y + 0.5f * (msy + mfy);
        float v2 = xv.z + 0.5f * (msz + mfz);
        float v3 = xv.w + 0.5f * (msw + mfw);

        // LayerNorm over H=64: 16-lane group (same t), 4 values/lane
        float sum = (v0 + v1) + (v2 + v3);
#pragma unroll
        for (int off = 1; off < 16; off <<= 1) sum += __shfl_xor(sum, off, 64);
        float mu = sum * (1.f / 64.f);
        float d0 = v0 - mu, d1 = v1 - mu, d2 = v2 - mu, d3 = v3 - mu;
        float var = (d0 * d0 + d1 * d1) + (d2 * d2 + d3 * d3);
#pragma unroll
        for (int off = 1; off < 16; off <<= 1) var += __shfl_xor(var, off, 64);
        var *= (1.f / 64.f);
        float inv = rsqrtf(var + LN_EPS);
        float4 o;
        o.x = d0 * inv * gv.x + bv.x;
        o.y = d1 * inv * gv.y + bv.y;
        o.z = d2 * inv * gv.z + bv.z;
        o.w = d3 * inv * gv.w + bv.w;
        out4[(long)n * 64 + lane] = o;
    }
}

// ---------------- mega kernel: scatter | t0 | a0 | t1 | a1 ----------------

__global__ __launch_bounds__(256, 2) void mega_kernel(
    const int* __restrict__ ei_s, const int* __restrict__ ei_f, int E,
    int* __restrict__ cnt2, int* __restrict__ col2,
    const float4* __restrict__ pred,
    const short8* __restrict__ wpack,
    const float* __restrict__ a0s, const float* __restrict__ a0f,
    const float4* __restrict__ g0, const float4* __restrict__ b0,
    const float* __restrict__ a1s, const float* __restrict__ a1f,
    const float4* __restrict__ g1, const float4* __restrict__ b1,
    unsigned short* __restrict__ h_s, unsigned short* __restrict__ h_f,
    float* __restrict__ esc_s, float* __restrict__ esc_f,
    float4* __restrict__ x_mid, float4* __restrict__ out,
    int* __restrict__ bar) {
    const int* cnt_s = cnt2;
    const int* cnt_f = cnt2 + NN;
    const int* col_s = col2;
    const int* col_f = col2 + (size_t)NN * CAP;

    scatter_body(ei_s, ei_f, cnt2, col2, E);
    gridbar(bar);

    transform_body(pred, wpack, a0s, wpack + 512, a0f, h_s, esc_s, h_f, esc_f);
    gridbar(bar);
    aggregate_body(pred, (const ushort4*)h_s, esc_s, cnt_s, col_s,
                   (const ushort4*)h_f, esc_f, cnt_f, col_f, g0, b0, x_mid);
    gridbar(bar);

    transform_body(x_mid, wpack + 1024, a1s, wpack + 1536, a1f, h_s, esc_s, h_f, esc_f);
    gridbar(bar);
    aggregate_body(x_mid, (const ushort4*)h_s, esc_s, cnt_s, col_s,
                   (const ushort4*)h_f, esc_f, cnt_f, col_f, g1, b1, out);
}

// ---------------- launch ----------------

extern "C" void kernel_launch(void* const* d_in, const int* in_sizes, int n_in,
                              void* d_out, int out_size, void* d_ws, size_t ws_size,
                              hipStream_t stream) {
    const float* pred = (const float*)d_in[0];
    const int* ei_s = (const int*)d_in[1];
    const int* ei_f = (const int*)d_in[2];
    const float* W0s = (const float*)d_in[3];
    const float* a0s = (const float*)d_in[4];
    const float* W0f = (const float*)d_in[5];
    const float* a0f = (const float*)d_in[6];
    const float* g0  = (const float*)d_in[7];
    const float* b0  = (const float*)d_in[8];
    const float* W1s = (const float*)d_in[9];
    const float* a1s = (const float*)d_in[10];
    const float* W1f = (const float*)d_in[11];
    const float* a1f = (const float*)d_in[12];
    const float* g1  = (const float*)d_in[13];
    const float* b1  = (const float*)d_in[14];
    const int E = in_sizes[1] / 2;  // 262144

    // workspace bump allocator (~51 MB)
    char* ws = (char*)d_ws;
    auto alloc = [&](size_t bytes) {
        char* p = ws;
        ws += (bytes + 255) & ~(size_t)255;
        return p;
    };
    int* cnt2 = (int*)alloc((size_t)2 * NN * sizeof(int));
    int* col2 = (int*)alloc((size_t)2 * NN * CAP * sizeof(int));
    short8* wpack = (short8*)alloc((size_t)4 * 512 * sizeof(short8));
    unsigned short* h_s = (unsigned short*)alloc((size_t)NT * HH * sizeof(unsigned short));
    unsigned short* h_f = (unsigned short*)alloc((size_t)NT * HH * sizeof(unsigned short));
    float* esc_s = (float*)alloc((size_t)NT * sizeof(float));
    float* esc_f = (float*)alloc((size_t)NT * sizeof(float));
    float* x_mid = (float*)alloc((size_t)NT * HH * sizeof(float));
    int* bar = (int*)alloc(2 * sizeof(int));

    // dispatch 1: zero counters + barrier state, pack W fragments
    prep_kernel<<<136, 256, 0, stream>>>(W0s, W0f, W1s, W1f, wpack, cnt2, bar);

    // dispatch 2: scatter | transform0 | aggregate0 | transform1 | aggregate1
    mega_kernel<<<MEGA_BLOCKS, 256, 0, stream>>>(
        ei_s, ei_f, E, cnt2, col2,
        (const float4*)pred, wpack,
        a0s, a0f, (const float4*)g0, (const float4*)b0,
        a1s, a1f, (const float4*)g1, (const float4*)b1,
        h_s, h_f, esc_s, esc_f,
        (float4*)x_mid, (float4*)d_out, bar);
}

// Round 6
// 216.051 us; speedup vs baseline: 2.7621x; 2.7621x over previous
//
#include <hip/hip_runtime.h>
#include <hip/hip_bf16.h>

#define NN 16384
#define TT 4
#define HH 64
#define NT (NN * TT)
#define CAP 128  // bucket capacity per node per edge-set; Poisson(16) => P(deg>=128) ~ 0
#define NEG_SLOPE 0.2f
#define LN_EPS 1e-5f

typedef __attribute__((ext_vector_type(8))) short short8;   // 8 bf16 (4 VGPRs)
typedef __attribute__((ext_vector_type(4))) float f32x4;    // MFMA accumulator

__device__ __forceinline__ float bf2f(unsigned short u) {
    return __uint_as_float((unsigned)u << 16);
}
// f32 -> bf16 RNE, layout-independent
__device__ __forceinline__ unsigned short f2bf(float f) {
    unsigned u = __float_as_uint(f);
    return (unsigned short)((u + 0x7FFF + ((u >> 16) & 1)) >> 16);
}

// ---------------- dispatch 1: zero counters + pack W fragments ----------------
// blocks 0..127: zero cnt2 (2*NN ints). blocks 128..135: pack the four 64x64 f32
// W matrices into bf16 MFMA B-fragment layout:
// wpack[mat*512 + (c*2+ks)*64 + lane] = short8 of W[k=ks*32+quad*8+j][n=c*16+m].

__global__ __launch_bounds__(256) void prep_kernel(
    const float* __restrict__ W0s_, const float* __restrict__ W0f_,
    const float* __restrict__ W1s_, const float* __restrict__ W1f_,
    short8* __restrict__ wpack, int* __restrict__ cnt2) {
    const int b = blockIdx.x;
    if (b < 128) {
        cnt2[b * 256 + threadIdx.x] = 0;
        return;
    }
    int id = (b - 128) * 256 + threadIdx.x;   // [0, 2048)
    int mat = id >> 9;
    int slot = id & 511;
    int lane = slot & 63;
    int cks = slot >> 6;
    int c = cks >> 1, ks = cks & 1;
    int m = lane & 15, quad = lane >> 4;
    const float* W = (mat == 0) ? W0s_ : (mat == 1) ? W0f_ : (mat == 2) ? W1s_ : W1f_;
    short8 v;
#pragma unroll
    for (int j = 0; j < 8; j++) {
        int k = ks * 32 + quad * 8 + j;
        int n = c * 16 + m;
        v[j] = (short)f2bf(W[k * 64 + n]);
    }
    wpack[id] = v;
}

// ------- full-width dual transform body (used for layer 0) -------
// v_mfma_f32_16x16x32_bf16. A-frag: A[m=lane&15][k=quad*8+j]. B-frag (KxN):
// B[k=quad*8+j][n=lane&15]. C/D: col=lane&15, row=quad*4+reg.
// Wave = 32 rows (2 row-tiles); block = 4 waves = 128 rows; 512 blocks = NT rows.
// Stores esc = exp(leakyrelu(score)) so the aggregate never runs exp (softmax is
// single-pass without max subtraction; logits are O(+-8)).

__device__ __forceinline__ void transform_body(
    int bid, const float4* __restrict__ x4,
    const short8* __restrict__ wp_s, const float* __restrict__ as_,
    const short8* __restrict__ wp_f, const float* __restrict__ af,
    unsigned short* __restrict__ h_s, float* __restrict__ esc_s,
    unsigned short* __restrict__ h_f, float* __restrict__ esc_f) {
    const int lane = threadIdx.x & 63;
    const int wv = threadIdx.x >> 6;
    const int m = lane & 15;
    const int quad = lane >> 4;

    short8 Bs[4][2], Bf[4][2];
#pragma unroll
    for (int c = 0; c < 4; c++) {
#pragma unroll
        for (int ks = 0; ks < 2; ks++) {
            Bs[c][ks] = wp_s[(c * 2 + ks) * 64 + lane];
            Bf[c][ks] = wp_f[(c * 2 + ks) * 64 + lane];
        }
    }
    float a_s[4], a_f[4];
#pragma unroll
    for (int c = 0; c < 4; c++) { a_s[c] = as_[c * 16 + m]; a_f[c] = af[c * 16 + m]; }

    const int rowbase = bid * 128 + wv * 32;
#pragma unroll
    for (int rt = 0; rt < 2; rt++) {
        const int row0 = rowbase + rt * 16;
        const long xbase = (long)(row0 + m) * 16 + quad * 2;
        float4 xa = x4[xbase];
        float4 xb = x4[xbase + 1];
        float4 xc = x4[xbase + 8];
        float4 xd = x4[xbase + 9];
        short8 A0, A1;
        A0[0] = (short)f2bf(xa.x); A0[1] = (short)f2bf(xa.y);
        A0[2] = (short)f2bf(xa.z); A0[3] = (short)f2bf(xa.w);
        A0[4] = (short)f2bf(xb.x); A0[5] = (short)f2bf(xb.y);
        A0[6] = (short)f2bf(xb.z); A0[7] = (short)f2bf(xb.w);
        A1[0] = (short)f2bf(xc.x); A1[1] = (short)f2bf(xc.y);
        A1[2] = (short)f2bf(xc.z); A1[3] = (short)f2bf(xc.w);
        A1[4] = (short)f2bf(xd.x); A1[5] = (short)f2bf(xd.y);
        A1[6] = (short)f2bf(xd.z); A1[7] = (short)f2bf(xd.w);

        f32x4 accs[4], accf[4];
#pragma unroll
        for (int c = 0; c < 4; c++) {
            accs[c] = (f32x4){0.f, 0.f, 0.f, 0.f};
            accf[c] = (f32x4){0.f, 0.f, 0.f, 0.f};
        }
#pragma unroll
        for (int c = 0; c < 4; c++) {
            accs[c] = __builtin_amdgcn_mfma_f32_16x16x32_bf16(A0, Bs[c][0], accs[c], 0, 0, 0);
            accs[c] = __builtin_amdgcn_mfma_f32_16x16x32_bf16(A1, Bs[c][1], accs[c], 0, 0, 0);
            accf[c] = __builtin_amdgcn_mfma_f32_16x16x32_bf16(A0, Bf[c][0], accf[c], 0, 0, 0);
            accf[c] = __builtin_amdgcn_mfma_f32_16x16x32_bf16(A1, Bf[c][1], accf[c], 0, 0, 0);
        }
#pragma unroll
        for (int reg = 0; reg < 4; reg++) {
            const int row = row0 + quad * 4 + reg;
            float ps = 0.f, pf = 0.f;
#pragma unroll
            for (int c = 0; c < 4; c++) {
                h_s[(long)row * 64 + c * 16 + m] = f2bf(accs[c][reg]);
                h_f[(long)row * 64 + c * 16 + m] = f2bf(accf[c][reg]);
                ps = fmaf(accs[c][reg], a_s[c], ps);
                pf = fmaf(accf[c][reg], a_f[c], pf);
            }
#pragma unroll
            for (int off = 1; off < 16; off <<= 1) {
                ps += __shfl_xor(ps, off, 64);
                pf += __shfl_xor(pf, off, 64);
            }
            if (m == 0) {
                float ls = (ps > 0.f) ? ps : NEG_SLOPE * ps;  // LeakyReLU folded in
                float lf = (pf > 0.f) ? pf : NEG_SLOPE * pf;
                esc_s[row] = __expf(ls);  // pre-exponentiated score
                esc_f[row] = __expf(lf);
            }
        }
    }
}

// ---------------- dispatch 2: scatter || transform0 (independent work) ----------------
// blocks 0..511: layer-0 transform (reads pred + wpack). blocks 512+: bucket-CSR
// atomic-ticket scatter, one edge per thread (needs cnt2 zeroed by prep).

__global__ __launch_bounds__(256) void st0_kernel(
    const int* __restrict__ ei_s, const int* __restrict__ ei_f, int E,
    int* __restrict__ cnt2, int* __restrict__ col2,
    const float4* __restrict__ pred, const short8* __restrict__ wpack,
    const float* __restrict__ a0s, const float* __restrict__ a0f,
    unsigned short* __restrict__ h_s, float* __restrict__ esc_s,
    unsigned short* __restrict__ h_f, float* __restrict__ esc_f) {
    if (blockIdx.x < 512) {
        transform_body(blockIdx.x, pred, wpack, a0s, wpack + 512, a0f,
                       h_s, esc_s, h_f, esc_f);
        return;
    }
    int e = (blockIdx.x - 512) * 256 + threadIdx.x;
    if (e >= 2 * E) return;
    if (e < E) {
        int d = ei_s[E + e];
        int pos = atomicAdd(&cnt2[d], 1);
        if (pos < CAP) col2[d * CAP + pos] = ei_s[e];
    } else {
        e -= E;
        int d = ei_f[E + e];
        int pos = atomicAdd(&cnt2[NN + d], 1);
        if (pos < CAP) col2[(long)NN * CAP + d * CAP + pos] = ei_f[e];
    }
}

// ---------------- r3-proven aggregate phase (device body) ----------------
// Wave = 1 node. Full edge list preloaded with one coalesced 64-wide load per
// set, indices broadcast via v_readlane (SGPR address math), gathers issued in
// independent batches of 8 per set, both sets interleaved (~16 loads in flight).
// lane: t = lane>>4, channels 4*(lane&15)..+3. Returns post-LN float4.

__device__ __forceinline__ float4 aggregate_node(
    int n, int lane, int t,
    const float4* __restrict__ x4,
    const ushort4* __restrict__ hs4, const float* __restrict__ escs,
    const int* __restrict__ cnts, const int* __restrict__ cols,
    const ushort4* __restrict__ hf4, const float* __restrict__ escf,
    const int* __restrict__ cntf, const int* __restrict__ colf,
    float4 gv, float4 bv) {
    int cS = cnts[n]; if (cS > CAP) cS = CAP;
    int cF = cntf[n]; if (cF > CAP) cF = CAP;
    cS = __builtin_amdgcn_readfirstlane(cS);
    cF = __builtin_amdgcn_readfirstlane(cF);
    const int* colS = cols + (long)n * CAP;
    const int* colF = colf + (long)n * CAP;

    int idxS = colS[lane];
    int idxF = colF[lane];
    if (lane >= cS) idxS = 0;
    if (lane >= cF) idxF = 0;

    const int cS64 = cS < 64 ? cS : 64;
    const int cF64 = cF < 64 ? cF : 64;

    float dS = 0.f, sx = 0.f, sy = 0.f, sz = 0.f, sw = 0.f;
    float dF = 0.f, fx = 0.f, fy = 0.f, fz = 0.f, fw = 0.f;

    const int nbS = (cS64 + 7) >> 3;
    const int nbF = (cF64 + 7) >> 3;
    const int nb = nbS > nbF ? nbS : nbF;

    for (int it = 0; it < nb; ++it) {
        const int j = it << 3;
        const bool doS = it < nbS;
        const bool doF = it < nbF;
        int sS[8], sF[8];
        float eS[8], eF[8];
        ushort4 hS[8], hF[8];

        if (doS) {
#pragma unroll
            for (int u = 0; u < 8; u++) sS[u] = __builtin_amdgcn_readlane(idxS, j + u);
#pragma unroll
            for (int u = 0; u < 8; u++) hS[u] = hs4[sS[u] * 64 + lane];
#pragma unroll
            for (int u = 0; u < 8; u++) eS[u] = escs[sS[u] * 4 + t];
        }
        if (doF) {
#pragma unroll
            for (int u = 0; u < 8; u++) sF[u] = __builtin_amdgcn_readlane(idxF, j + u);
#pragma unroll
            for (int u = 0; u < 8; u++) hF[u] = hf4[sF[u] * 64 + lane];
#pragma unroll
            for (int u = 0; u < 8; u++) eF[u] = escf[sF[u] * 4 + t];
        }
        if (doS) {
#pragma unroll
            for (int u = 0; u < 8; u++) {
                float e = (j + u < cS64) ? eS[u] : 0.f;
                dS += e;
                sx = fmaf(e, bf2f(hS[u].x), sx);
                sy = fmaf(e, bf2f(hS[u].y), sy);
                sz = fmaf(e, bf2f(hS[u].z), sz);
                sw = fmaf(e, bf2f(hS[u].w), sw);
            }
        }
        if (doF) {
#pragma unroll
            for (int u = 0; u < 8; u++) {
                float e = (j + u < cF64) ? eF[u] : 0.f;
                dF += e;
                fx = fmaf(e, bf2f(hF[u].x), fx);
                fy = fmaf(e, bf2f(hF[u].y), fy);
                fz = fmaf(e, bf2f(hF[u].z), fz);
                fw = fmaf(e, bf2f(hF[u].w), fw);
            }
        }
    }

    // tail beyond 64 edges (statistically unreachable; correctness guard)
    for (int j2 = 64; j2 < cS; ++j2) {
        int s0 = colS[j2];
        float e0 = escs[s0 * 4 + t];
        ushort4 h0 = hs4[(long)s0 * 64 + lane];
        dS += e0;
        sx = fmaf(e0, bf2f(h0.x), sx);
        sy = fmaf(e0, bf2f(h0.y), sy);
        sz = fmaf(e0, bf2f(h0.z), sz);
        sw = fmaf(e0, bf2f(h0.w), sw);
    }
    for (int j2 = 64; j2 < cF; ++j2) {
        int s0 = colF[j2];
        float e0 = escf[s0 * 4 + t];
        ushort4 h0 = hf4[(long)s0 * 64 + lane];
        dF += e0;
        fx = fmaf(e0, bf2f(h0.x), fx);
        fy = fmaf(e0, bf2f(h0.y), fy);
        fz = fmaf(e0, bf2f(h0.z), fz);
        fw = fmaf(e0, bf2f(h0.w), fw);
    }

    float msx = 0.f, msy = 0.f, msz = 0.f, msw = 0.f;
    if (dS > 0.f) {
        float r = 1.f / dS;
        msx = sx * r; msy = sy * r; msz = sz * r; msw = sw * r;
    }
    float mfx = 0.f, mfy = 0.f, mfz = 0.f, mfw = 0.f;
    if (dF > 0.f) {
        float r = 1.f / dF;
        mfx = fx * r; mfy = fy * r; mfz = fz * r; mfw = fw * r;
    }

    float4 xv = x4[(long)n * 64 + lane];  // x[n][t][4*ci..+3]
    float v0 = xv.x + 0.5f * (msx + mfx);
    float v1 = xv.y + 0.5f * (msy + mfy);
    float v2 = xv.z + 0.5f * (msz + mfz);
    float v3 = xv.w + 0.5f * (msw + mfw);

    // LayerNorm over H=64: 16-lane group (same t), 4 values/lane
    float sum = (v0 + v1) + (v2 + v3);
#pragma unroll
    for (int off = 1; off < 16; off <<= 1) sum += __shfl_xor(sum, off, 64);
    float mu = sum * (1.f / 64.f);
    float d0 = v0 - mu, d1 = v1 - mu, d2 = v2 - mu, d3 = v3 - mu;
    float var = (d0 * d0 + d1 * d1) + (d2 * d2 + d3 * d3);
#pragma unroll
    for (int off = 1; off < 16; off <<= 1) var += __shfl_xor(var, off, 64);
    var *= (1.f / 64.f);
    float inv = rsqrtf(var + LN_EPS);
    float4 o;
    o.x = d0 * inv * gv.x + bv.x;
    o.y = d1 * inv * gv.y + bv.y;
    o.z = d2 * inv * gv.z + bv.z;
    o.w = d3 * inv * gv.w + bv.w;
    return o;
}

// ---------------- dispatch 3: aggregate0 + transform1 fused ----------------
// Phase A: r3 aggregate (wave = 1 node, block = 4 nodes = 16 rows), writes x_mid
// (f32, layer-1 residual) and the LN output as bf16 into LDS.
// Phase B: the block's 16 rows are exactly one MFMA row-tile. Wave wv computes
// output-channel chunk wv (c=wv) for both sets: 4 MFMAs. Scores need all 64
// channels -> per-wave partials summed via LDS; wave 0 writes esc1.
// Layer-1 h/esc are double-buffered vs layer-0 (phase A of other blocks still
// gathers layer-0 h while this block writes layer-1 h).

__global__ __launch_bounds__(256) void a0t1_kernel(
    const float4* __restrict__ pred,
    const ushort4* __restrict__ hs4, const float* __restrict__ escs,
    const int* __restrict__ cnts, const int* __restrict__ cols,
    const ushort4* __restrict__ hf4, const float* __restrict__ escf,
    const int* __restrict__ cntf, const int* __restrict__ colf,
    const float4* __restrict__ g4, const float4* __restrict__ b4,
    float4* __restrict__ xmid4,
    const short8* __restrict__ wp1s, const short8* __restrict__ wp1f,
    const float* __restrict__ a1s, const float* __restrict__ a1f,
    unsigned short* __restrict__ h1_s, float* __restrict__ esc1_s,
    unsigned short* __restrict__ h1_f, float* __restrict__ esc1_f) {
    __shared__ __align__(16) ushort4 xb4[16][16];  // [row_local][ci] 4 bf16 ch
    __shared__ float psumS[4][16];
    __shared__ float psumF[4][16];
    const int wv = threadIdx.x >> 6;
    const int lane = threadIdx.x & 63;
    const int t = lane >> 4;
    const int ci = lane & 15;
    const int n0 = blockIdx.x * 4;
    const int n = n0 + wv;

    // ---- phase A: layer-0 aggregate + residual + LN ----
    float4 o = aggregate_node(n, lane, t, pred, hs4, escs, cnts, cols,
                              hf4, escf, cntf, colf, g4[ci], b4[ci]);
    xmid4[(long)n * 64 + lane] = o;  // f32 for layer-1 residual
    ushort4 xu;
    xu.x = f2bf(o.x); xu.y = f2bf(o.y); xu.z = f2bf(o.z); xu.w = f2bf(o.w);
    xb4[wv * 4 + t][ci] = xu;        // row_local = wv*4+t, channels 4ci..+3
    __syncthreads();

    // ---- phase B: layer-1 transform for the block's 16 rows; c-chunk = wv ----
    const int m = lane & 15;
    const int quad = lane >> 4;
    const short8* xbs8 = (const short8*)xb4;     // row stride = 8 short8
    short8 A0 = xbs8[m * 8 + quad];              // A[m][k=quad*8+j]
    short8 A1 = xbs8[m * 8 + 4 + quad];          // A[m][k=32+quad*8+j]
    short8 Bs0 = wp1s[(wv * 2 + 0) * 64 + lane];
    short8 Bs1 = wp1s[(wv * 2 + 1) * 64 + lane];
    short8 Bf0 = wp1f[(wv * 2 + 0) * 64 + lane];
    short8 Bf1 = wp1f[(wv * 2 + 1) * 64 + lane];
    f32x4 accs = (f32x4){0.f, 0.f, 0.f, 0.f};
    f32x4 accf = (f32x4){0.f, 0.f, 0.f, 0.f};
    accs = __builtin_amdgcn_mfma_f32_16x16x32_bf16(A0, Bs0, accs, 0, 0, 0);
    accs = __builtin_amdgcn_mfma_f32_16x16x32_bf16(A1, Bs1, accs, 0, 0, 0);
    accf = __builtin_amdgcn_mfma_f32_16x16x32_bf16(A0, Bf0, accf, 0, 0, 0);
    accf = __builtin_amdgcn_mfma_f32_16x16x32_bf16(A1, Bf1, accf, 0, 0, 0);

    const float av_s = a1s[wv * 16 + m];
    const float av_f = a1f[wv * 16 + m];
#pragma unroll
    for (int reg = 0; reg < 4; reg++) {
        const int row = n0 * 4 + quad * 4 + reg;           // row_local = quad*4+reg
        h1_s[(long)row * 64 + wv * 16 + m] = f2bf(accs[reg]);
        h1_f[(long)row * 64 + wv * 16 + m] = f2bf(accf[reg]);
        float pS = accs[reg] * av_s;
        float pF = accf[reg] * av_f;
#pragma unroll
        for (int off = 1; off < 16; off <<= 1) {
            pS += __shfl_xor(pS, off, 64);
            pF += __shfl_xor(pF, off, 64);
        }
        if (m == 0) {
            psumS[wv][quad * 4 + reg] = pS;  // partial over channels wv*16..+15
            psumF[wv][quad * 4 + reg] = pF;
        }
    }
    __syncthreads();
    if (threadIdx.x < 16) {
        const int r = threadIdx.x;
        float sS = (psumS[0][r] + psumS[1][r]) + (psumS[2][r] + psumS[3][r]);
        float sF = (psumF[0][r] + psumF[1][r]) + (psumF[2][r] + psumF[3][r]);
        float ls = (sS > 0.f) ? sS : NEG_SLOPE * sS;   // LeakyReLU folded in
        float lf = (sF > 0.f) ? sF : NEG_SLOPE * sF;
        esc1_s[n0 * 4 + r] = __expf(ls);
        esc1_f[n0 * 4 + r] = __expf(lf);
    }
}

// ---------------- dispatch 4: aggregate1 (writes final output) ----------------

__global__ __launch_bounds__(256) void a1_kernel(
    const float4* __restrict__ x4,
    const ushort4* __restrict__ hs4, const float* __restrict__ escs,
    const int* __restrict__ cnts, const int* __restrict__ cols,
    const ushort4* __restrict__ hf4, const float* __restrict__ escf,
    const int* __restrict__ cntf, const int* __restrict__ colf,
    const float4* __restrict__ g4, const float4* __restrict__ b4,
    float4* __restrict__ out4) {
    const int wv = threadIdx.x >> 6;
    const int lane = threadIdx.x & 63;
    const int t = lane >> 4;
    const int ci = lane & 15;
    const int n = blockIdx.x * 4 + wv;
    float4 o = aggregate_node(n, lane, t, x4, hs4, escs, cnts, cols,
                              hf4, escf, cntf, colf, g4[ci], b4[ci]);
    out4[(long)n * 64 + lane] = o;
}

// ---------------- launch ----------------

extern "C" void kernel_launch(void* const* d_in, const int* in_sizes, int n_in,
                              void* d_out, int out_size, void* d_ws, size_t ws_size,
                              hipStream_t stream) {
    const float* pred = (const float*)d_in[0];
    const int* ei_s = (const int*)d_in[1];
    const int* ei_f = (const int*)d_in[2];
    const float* W0s = (const float*)d_in[3];
    const float* a0s = (const float*)d_in[4];
    const float* W0f = (const float*)d_in[5];
    const float* a0f = (const float*)d_in[6];
    const float* g0  = (const float*)d_in[7];
    const float* b0  = (const float*)d_in[8];
    const float* W1s = (const float*)d_in[9];
    const float* a1s = (const float*)d_in[10];
    const float* W1f = (const float*)d_in[11];
    const float* a1f = (const float*)d_in[12];
    const float* g1  = (const float*)d_in[13];
    const float* b1  = (const float*)d_in[14];
    const int E = in_sizes[1] / 2;  // 262144

    // workspace bump allocator (~68 MB)
    char* ws = (char*)d_ws;
    auto alloc = [&](size_t bytes) {
        char* p = ws;
        ws += (bytes + 255) & ~(size_t)255;
        return p;
    };
    int* cnt2 = (int*)alloc((size_t)2 * NN * sizeof(int));
    int* col2 = (int*)alloc((size_t)2 * NN * CAP * sizeof(int));
    short8* wpack = (short8*)alloc((size_t)4 * 512 * sizeof(short8));
    unsigned short* h0_s = (unsigned short*)alloc((size_t)NT * HH * sizeof(unsigned short));
    unsigned short* h0_f = (unsigned short*)alloc((size_t)NT * HH * sizeof(unsigned short));
    unsigned short* h1_s = (unsigned short*)alloc((size_t)NT * HH * sizeof(unsigned short));
    unsigned short* h1_f = (unsigned short*)alloc((size_t)NT * HH * sizeof(unsigned short));
    float* esc0_s = (float*)alloc((size_t)NT * sizeof(float));
    float* esc0_f = (float*)alloc((size_t)NT * sizeof(float));
    float* esc1_s = (float*)alloc((size_t)NT * sizeof(float));
    float* esc1_f = (float*)alloc((size_t)NT * sizeof(float));
    float* x_mid = (float*)alloc((size_t)NT * HH * sizeof(float));

    const int* cnt_s = cnt2;
    const int* cnt_f = cnt2 + NN;
    const int* col_s = col2;
    const int* col_f = col2 + (size_t)NN * CAP;

    const int SB = (2 * E + 255) / 256;  // scatter blocks

    // 1) zero counters + pack W fragments
    prep_kernel<<<136, 256, 0, stream>>>(W0s, W0f, W1s, W1f, wpack, cnt2);

    // 2) scatter || transform0
    st0_kernel<<<512 + SB, 256, 0, stream>>>(
        ei_s, ei_f, E, cnt2, col2,
        (const float4*)pred, wpack, a0s, a0f,
        h0_s, esc0_s, h0_f, esc0_f);

    // 3) aggregate0 + transform1 (per-block row-tile fusion)
    a0t1_kernel<<<NN / 4, 256, 0, stream>>>(
        (const float4*)pred,
        (const ushort4*)h0_s, esc0_s, cnt_s, col_s,
        (const ushort4*)h0_f, esc0_f, cnt_f, col_f,
        (const float4*)g0, (const float4*)b0,
        (float4*)x_mid,
        wpack + 1024, wpack + 1536, a1s, a1f,
        h1_s, esc1_s, h1_f, esc1_f);

    // 4) aggregate1 -> output
    a1_kernel<<<NN / 4, 256, 0, stream>>>(
        (const float4*)x_mid,
        (const ushort4*)h1_s, esc1_s, cnt_s, col_s,
        (const ushort4*)h1_f, esc1_f, cnt_f, col_f,
        (const float4*)g1, (const float4*)b1, (float4*)d_out);
}